// Round 1
// baseline (69.566 us; speedup 1.0000x reference)
//
#include <hip/hip_runtime.h>
#include <math.h>

#define IMG_W 512
#define OW 113
#define N_WIN (113 * 113)

__device__ __forceinline__ float max4(float4 v) { return fmaxf(fmaxf(v.x, v.y), fmaxf(v.z, v.w)); }
__device__ __forceinline__ float min4(float4 v) { return fminf(fminf(v.x, v.y), fminf(v.z, v.w)); }

__global__ __launch_bounds__(256) void fd_kernel(const float* __restrict__ X,
                                                 float* __restrict__ out) {
    const int w  = blockIdx.x;
    const int ti = w / OW;          // window row (tile units, pixels = ti*4)
    const int tj = w - ti * OW;     // window col
    const int t  = threadIdx.x;
    const int a  = t >> 4;          // tile row within window 0..15
    const int b  = t & 15;          // tile col within window 0..15

    // ---- level s=4: each thread owns one 4x4 pixel tile ----
    const int row0 = (ti + a) * 4;
    const int col0 = (tj + b) * 4;
    const float* p = X + row0 * IMG_W + col0;   // 16B-aligned
    float4 r0 = *(const float4*)(p);
    float4 r1 = *(const float4*)(p + IMG_W);
    float4 r2 = *(const float4*)(p + 2 * IMG_W);
    float4 r3 = *(const float4*)(p + 3 * IMG_W);

    float mx = fmaxf(fmaxf(max4(r0), max4(r1)), fmaxf(max4(r2), max4(r3)));
    float mn = fminf(fminf(min4(r0), min4(r1)), fminf(min4(r2), min4(r3)));

    __shared__ float smax[16][16], smin[16][16];
    __shared__ float s8max[8][8],  s8min[8][8];
    __shared__ float s16max[4][4], s16min[4][4];
    __shared__ float s32max[2][2], s32min[2][2];
    __shared__ float wsum[4];

    smax[a][b] = mx;
    smin[a][b] = mn;

    // d4 = sum over 256 tiles of (max-min): wave reduce + LDS combine
    float v4 = mx - mn;
    #pragma unroll
    for (int off = 32; off; off >>= 1) v4 += __shfl_down(v4, off, 64);
    const int lane = t & 63, wid = t >> 6;
    if (lane == 0) wsum[wid] = v4;
    __syncthreads();

    // ---- level s=8: 8x8 blocks, each 2x2 tiles (wave 0 only) ----
    float d8 = 0.f;
    if (t < 64) {
        const int a2 = t >> 3, b2 = t & 7;
        float bm = fmaxf(fmaxf(smax[2*a2][2*b2],   smax[2*a2][2*b2+1]),
                         fmaxf(smax[2*a2+1][2*b2], smax[2*a2+1][2*b2+1]));
        float bn = fminf(fminf(smin[2*a2][2*b2],   smin[2*a2][2*b2+1]),
                         fminf(smin[2*a2+1][2*b2], smin[2*a2+1][2*b2+1]));
        s8max[a2][b2] = bm;
        s8min[a2][b2] = bn;
        float v8 = bm - bn;
        #pragma unroll
        for (int off = 32; off; off >>= 1) v8 += __shfl_down(v8, off, 64);
        d8 = v8;   // valid in lane 0 (== thread 0)
    }
    __syncthreads();

    // ---- level s=16: 4x4 blocks ----
    float d16 = 0.f;
    if (t < 64) {
        float v16 = 0.f;
        if (t < 16) {
            const int a3 = t >> 2, b3 = t & 3;
            float bm = fmaxf(fmaxf(s8max[2*a3][2*b3],   s8max[2*a3][2*b3+1]),
                             fmaxf(s8max[2*a3+1][2*b3], s8max[2*a3+1][2*b3+1]));
            float bn = fminf(fminf(s8min[2*a3][2*b3],   s8min[2*a3][2*b3+1]),
                             fminf(s8min[2*a3+1][2*b3], s8min[2*a3+1][2*b3+1]));
            s16max[a3][b3] = bm;
            s16min[a3][b3] = bn;
            v16 = bm - bn;
        }
        #pragma unroll
        for (int off = 32; off; off >>= 1) v16 += __shfl_down(v16, off, 64);
        d16 = v16;
    }
    __syncthreads();

    // ---- level s=32: 2x2 blocks ----
    float d32 = 0.f;
    if (t < 64) {
        float v32 = 0.f;
        if (t < 4) {
            const int a4 = t >> 1, b4 = t & 1;
            float bm = fmaxf(fmaxf(s16max[2*a4][2*b4],   s16max[2*a4][2*b4+1]),
                             fmaxf(s16max[2*a4+1][2*b4], s16max[2*a4+1][2*b4+1]));
            float bn = fminf(fminf(s16min[2*a4][2*b4],   s16min[2*a4][2*b4+1]),
                             fminf(s16min[2*a4+1][2*b4], s16min[2*a4+1][2*b4+1]));
            s32max[a4][b4] = bm;
            s32min[a4][b4] = bn;
            v32 = bm - bn;
        }
        #pragma unroll
        for (int off = 32; off; off >>= 1) v32 += __shfl_down(v32, off, 64);
        d32 = v32;
    }
    __syncthreads();

    // ---- level s=64 + final slope (thread 0) ----
    if (t == 0) {
        float bm = fmaxf(fmaxf(s32max[0][0], s32max[0][1]),
                         fmaxf(s32max[1][0], s32max[1][1]));
        float bn = fminf(fminf(s32min[0][0], s32min[0][1]),
                         fminf(s32min[1][0], s32min[1][1]));
        float d64 = bm - bn;
        float d4  = wsum[0] + wsum[1] + wsum[2] + wsum[3];

        // ln(s_k) = k*ln2 for k=6..2; denom = ln2^2 * (36+25+16+9+4) = ln2^2 * 90
        // fd = -(sum_k k*ln2*ln(d_k)) / (ln2^2*90) = -(sum_k k*ln(d_k)) / (90*ln2)
        const float LN2 = 0.69314718055994530942f;
        float num = 6.f * logf(d64) + 5.f * logf(d32) + 4.f * logf(d16)
                  + 3.f * logf(d8)  + 2.f * logf(d4);
        out[w] = -num / (90.0f * LN2);
    }
}

extern "C" void kernel_launch(void* const* d_in, const int* in_sizes, int n_in,
                              void* d_out, int out_size, void* d_ws, size_t ws_size,
                              hipStream_t stream) {
    const float* X = (const float*)d_in[0];
    float* out = (float*)d_out;
    fd_kernel<<<N_WIN, 256, 0, stream>>>(X, out);
}

// Round 2
// 61.229 us; speedup vs baseline: 1.1362x; 1.1362x over previous
//
#include <hip/hip_runtime.h>
#include <math.h>

#define IMG_W 512
#define OW 113
#define N_WIN (113 * 113)
#define LSTRIDE 128          // row stride of all diff arrays in ws (floats)

// ws layout (floats): diff4 @0, diff8 @16384, diff16 @32768, diff32 @49152, diff64 @65536
#define OFF4  0
#define OFF8  16384
#define OFF16 32768
#define OFF32 49152
#define OFF64 65536

__device__ __forceinline__ float max4f(float4 v) { return fmaxf(fmaxf(v.x, v.y), fmaxf(v.z, v.w)); }
__device__ __forceinline__ float min4f(float4 v) { return fminf(fminf(v.x, v.y), fminf(v.z, v.w)); }

// K1: build the global tile pyramid diffs.
// Grid 16x16 blocks; block (bi,bj) produces the 8x8 patch [r0..r0+7]x[c0..c0+7]
// of every diff level. Needs tiles [r0..r0+22] (clamped; clamped entries are
// never consumed downstream).
__global__ __launch_bounds__(256) void fd_pyramid(const float* __restrict__ X,
                                                  float* __restrict__ ws) {
    float* diff4  = ws + OFF4;
    float* diff8  = ws + OFF8;
    float* diff16 = ws + OFF16;
    float* diff32 = ws + OFF32;
    float* diff64 = ws + OFF64;

    const int bi = blockIdx.x >> 4;
    const int bj = blockIdx.x & 15;
    const int r0 = bi * 8, c0 = bj * 8;
    const int t = threadIdx.x;

    __shared__ float tmax[23][24], tmin[23][24];
    __shared__ float p8x[22][24],  p8n[22][24];
    __shared__ float p16x[20][24], p16n[20][24];
    __shared__ float p32x[16][24], p32n[16][24];

    // ---- stage: per-4x4-tile max/min for 23x23 tile region ----
    for (int idx = t; idx < 23 * 23; idx += 256) {
        const int lr = idx / 23, lc = idx - lr * 23;
        const int gr = min(r0 + lr, 127);
        const int gc = min(c0 + lc, 127);
        const float* p = X + (gr * 4) * IMG_W + gc * 4;
        float4 a = *(const float4*)(p);
        float4 b = *(const float4*)(p + IMG_W);
        float4 c = *(const float4*)(p + 2 * IMG_W);
        float4 d = *(const float4*)(p + 3 * IMG_W);
        tmax[lr][lc] = fmaxf(fmaxf(max4f(a), max4f(b)), fmaxf(max4f(c), max4f(d)));
        tmin[lr][lc] = fminf(fminf(min4f(a), min4f(b)), fminf(min4f(c), min4f(d)));
    }
    __syncthreads();

    // ---- level 8 (2x2 tiles), plus diff4 writes ----
    for (int idx = t; idx < 22 * 22; idx += 256) {
        const int lr = idx / 22, lc = idx - lr * 22;
        float x = fmaxf(fmaxf(tmax[lr][lc],     tmax[lr][lc + 1]),
                        fmaxf(tmax[lr + 1][lc], tmax[lr + 1][lc + 1]));
        float n = fminf(fminf(tmin[lr][lc],     tmin[lr][lc + 1]),
                        fminf(tmin[lr + 1][lc], tmin[lr + 1][lc + 1]));
        p8x[lr][lc] = x;
        p8n[lr][lc] = n;
        if (lr < 8 && lc < 8) {
            diff4[(r0 + lr) * LSTRIDE + c0 + lc] = tmax[lr][lc] - tmin[lr][lc];
            diff8[(r0 + lr) * LSTRIDE + c0 + lc] = x - n;
        }
    }
    __syncthreads();

    // ---- level 16 (2x2 of p8 at stride 2) ----
    for (int idx = t; idx < 20 * 20; idx += 256) {
        const int lr = idx / 20, lc = idx - lr * 20;
        float x = fmaxf(fmaxf(p8x[lr][lc],     p8x[lr][lc + 2]),
                        fmaxf(p8x[lr + 2][lc], p8x[lr + 2][lc + 2]));
        float n = fminf(fminf(p8n[lr][lc],     p8n[lr][lc + 2]),
                        fminf(p8n[lr + 2][lc], p8n[lr + 2][lc + 2]));
        p16x[lr][lc] = x;
        p16n[lr][lc] = n;
        if (lr < 8 && lc < 8)
            diff16[(r0 + lr) * LSTRIDE + c0 + lc] = x - n;
    }
    __syncthreads();

    // ---- level 32 (2x2 of p16 at stride 4) ----
    for (int idx = t; idx < 16 * 16; idx += 256) {
        const int lr = idx >> 4, lc = idx & 15;
        float x = fmaxf(fmaxf(p16x[lr][lc],     p16x[lr][lc + 4]),
                        fmaxf(p16x[lr + 4][lc], p16x[lr + 4][lc + 4]));
        float n = fminf(fminf(p16n[lr][lc],     p16n[lr][lc + 4]),
                        fminf(p16n[lr + 4][lc], p16n[lr + 4][lc + 4]));
        p32x[lr][lc] = x;
        p32n[lr][lc] = n;
        if (lr < 8 && lc < 8)
            diff32[(r0 + lr) * LSTRIDE + c0 + lc] = x - n;
    }
    __syncthreads();

    // ---- level 64 (2x2 of p32 at stride 8) ----
    if (t < 64) {
        const int lr = t >> 3, lc = t & 7;
        float x = fmaxf(fmaxf(p32x[lr][lc],     p32x[lr][lc + 8]),
                        fmaxf(p32x[lr + 8][lc], p32x[lr + 8][lc + 8]));
        float n = fminf(fminf(p32n[lr][lc],     p32n[lr][lc + 8]),
                        fminf(p32n[lr + 8][lc], p32n[lr + 8][lc + 8]));
        diff64[(r0 + lr) * LSTRIDE + c0 + lc] = x - n;
    }
}

// K2: per-window strided box sums of the diff levels + slope.
__global__ __launch_bounds__(256) void fd_final(const float* __restrict__ ws,
                                                float* __restrict__ out) {
    const int w = blockIdx.x * 256 + threadIdx.x;
    if (w >= N_WIN) return;
    const int ti = w / OW;
    const int tj = w - ti * OW;

    const float* diff4  = ws + OFF4;
    const float* diff8  = ws + OFF8;
    const float* diff16 = ws + OFF16;
    const float* diff32 = ws + OFF32;
    const float* diff64 = ws + OFF64;

    float d4 = 0.f;
    #pragma unroll
    for (int a = 0; a < 16; ++a) {
        const float* row = diff4 + (ti + a) * LSTRIDE + tj;
        #pragma unroll
        for (int b = 0; b < 16; ++b) d4 += row[b];
    }
    float d8 = 0.f;
    #pragma unroll
    for (int a = 0; a < 8; ++a) {
        const float* row = diff8 + (ti + 2 * a) * LSTRIDE + tj;
        #pragma unroll
        for (int b = 0; b < 8; ++b) d8 += row[2 * b];
    }
    float d16 = 0.f;
    #pragma unroll
    for (int a = 0; a < 4; ++a) {
        const float* row = diff16 + (ti + 4 * a) * LSTRIDE + tj;
        #pragma unroll
        for (int b = 0; b < 4; ++b) d16 += row[4 * b];
    }
    float d32 = 0.f;
    #pragma unroll
    for (int a = 0; a < 2; ++a) {
        const float* row = diff32 + (ti + 8 * a) * LSTRIDE + tj;
        #pragma unroll
        for (int b = 0; b < 2; ++b) d32 += row[8 * b];
    }
    const float d64 = diff64[ti * LSTRIDE + tj];

    const float LN2 = 0.69314718055994530942f;
    const float num = 6.f * logf(d64) + 5.f * logf(d32) + 4.f * logf(d16)
                    + 3.f * logf(d8)  + 2.f * logf(d4);
    out[w] = -num / (90.0f * LN2);
}

extern "C" void kernel_launch(void* const* d_in, const int* in_sizes, int n_in,
                              void* d_out, int out_size, void* d_ws, size_t ws_size,
                              hipStream_t stream) {
    const float* X = (const float*)d_in[0];
    float* out = (float*)d_out;
    float* ws = (float*)d_ws;
    fd_pyramid<<<256, 256, 0, stream>>>(X, ws);
    fd_final<<<(N_WIN + 255) / 256, 256, 0, stream>>>(ws, out);
}

// Round 3
// 58.489 us; speedup vs baseline: 1.1894x; 1.0468x over previous
//
#include <hip/hip_runtime.h>
#include <math.h>

#define IMG_W 512
#define OW 113
#define DS 27   // diff-array LDS stride: 4-part offset 4p*27 %32 spreads banks -> exactly 2-way (free)

__device__ __forceinline__ float max4f(float4 v) { return fmaxf(fmaxf(v.x, v.y), fmaxf(v.z, v.w)); }
__device__ __forceinline__ float min4f(float4 v) { return fminf(fminf(v.x, v.y), fminf(v.z, v.w)); }

// One block = one 8x8 patch of windows. Builds the 23x23-tile min/max pyramid
// for its halo region in LDS, then sums per-window box diffs directly from LDS.
// Grid: 15x15 = 225 blocks (windows 0..119, guarded to 0..112).
__global__ __launch_bounds__(256) void fd_fused(const float* __restrict__ X,
                                                float* __restrict__ out) {
    const int bi = blockIdx.x / 15;
    const int bj = blockIdx.x - bi * 15;
    const int t  = threadIdx.x;

    __shared__ float tmax[23][24], tmin[23][24];
    __shared__ float p8x[22][24],  p8n[22][24];
    __shared__ float p16x[20][24], p16n[20][24];
    __shared__ float p32x[16][24], p32n[16][24];
    __shared__ float df4[23][DS], df8[22][DS], df16[20][DS], df32[16][DS];

    // ---- stage: per-4x4-pixel-tile max/min for the 23x23 tile halo ----
    for (int idx = t; idx < 23 * 23; idx += 256) {
        const int lr = idx / 23, lc = idx - lr * 23;
        const int gr = min(bi * 8 + lr, 127);   // clamped entries feed only out-of-range windows
        const int gc = min(bj * 8 + lc, 127);
        const float* p = X + (gr * 4) * IMG_W + gc * 4;
        float4 a = *(const float4*)(p);
        float4 b = *(const float4*)(p + IMG_W);
        float4 c = *(const float4*)(p + 2 * IMG_W);
        float4 d = *(const float4*)(p + 3 * IMG_W);
        float mx = fmaxf(fmaxf(max4f(a), max4f(b)), fmaxf(max4f(c), max4f(d)));
        float mn = fminf(fminf(min4f(a), min4f(b)), fminf(min4f(c), min4f(d)));
        tmax[lr][lc] = mx;
        tmin[lr][lc] = mn;
        df4[lr][lc]  = mx - mn;
    }
    __syncthreads();

    // ---- level 8: 2x2 tile pool, 22x22 ----
    for (int idx = t; idx < 22 * 22; idx += 256) {
        const int lr = idx / 22, lc = idx - lr * 22;
        float x = fmaxf(fmaxf(tmax[lr][lc],     tmax[lr][lc + 1]),
                        fmaxf(tmax[lr + 1][lc], tmax[lr + 1][lc + 1]));
        float n = fminf(fminf(tmin[lr][lc],     tmin[lr][lc + 1]),
                        fminf(tmin[lr + 1][lc], tmin[lr + 1][lc + 1]));
        p8x[lr][lc] = x;
        p8n[lr][lc] = n;
        df8[lr][lc] = x - n;
    }
    __syncthreads();

    // ---- level 16: 2x2 of p8 at stride 2, 20x20 ----
    for (int idx = t; idx < 20 * 20; idx += 256) {
        const int lr = idx / 20, lc = idx - lr * 20;
        float x = fmaxf(fmaxf(p8x[lr][lc],     p8x[lr][lc + 2]),
                        fmaxf(p8x[lr + 2][lc], p8x[lr + 2][lc + 2]));
        float n = fminf(fminf(p8n[lr][lc],     p8n[lr][lc + 2]),
                        fminf(p8n[lr + 2][lc], p8n[lr + 2][lc + 2]));
        p16x[lr][lc] = x;
        p16n[lr][lc] = n;
        df16[lr][lc] = x - n;
    }
    __syncthreads();

    // ---- level 32: 2x2 of p16 at stride 4, 16x16 (exactly 256) ----
    {
        const int lr = t >> 4, lc = t & 15;
        float x = fmaxf(fmaxf(p16x[lr][lc],     p16x[lr][lc + 4]),
                        fmaxf(p16x[lr + 4][lc], p16x[lr + 4][lc + 4]));
        float n = fminf(fminf(p16n[lr][lc],     p16n[lr][lc + 4]),
                        fminf(p16n[lr + 4][lc], p16n[lr + 4][lc + 4]));
        p32x[lr][lc] = x;
        p32n[lr][lc] = n;
        df32[lr][lc] = x - n;
    }
    __syncthreads();

    // ---- final: 4 threads per window sum the box diffs from LDS ----
    const int q  = t >> 2;        // window 0..63
    const int pp = t & 3;         // part 0..3
    const int wi = q >> 3, wj = q & 7;

    float d4 = 0.f;
    #pragma unroll
    for (int r = 0; r < 4; ++r) {
        const float* row = &df4[wi + 4 * pp + r][wj];
        #pragma unroll
        for (int b = 0; b < 16; ++b) d4 += row[b];
    }
    float d8 = 0.f;
    #pragma unroll
    for (int r = 0; r < 2; ++r) {
        const float* row = &df8[wi + 2 * (2 * pp + r)][wj];
        #pragma unroll
        for (int b = 0; b < 8; ++b) d8 += row[2 * b];
    }
    float d16 = 0.f;
    {
        const float* row = &df16[wi + 4 * pp][wj];
        #pragma unroll
        for (int b = 0; b < 4; ++b) d16 += row[4 * b];
    }
    float d32 = df32[wi + 8 * (pp >> 1)][wj + 8 * (pp & 1)];
    float d64 = 0.f;
    if (pp == 0) {
        float x = fmaxf(fmaxf(p32x[wi][wj],     p32x[wi][wj + 8]),
                        fmaxf(p32x[wi + 8][wj], p32x[wi + 8][wj + 8]));
        float n = fminf(fminf(p32n[wi][wj],     p32n[wi][wj + 8]),
                        fminf(p32n[wi + 8][wj], p32n[wi + 8][wj + 8]));
        d64 = x - n;
    }

    // combine the 4 parts (lanes 4q..4q+3 are within one wave)
    d4  += __shfl_down(d4,  2, 64);  d4  += __shfl_down(d4,  1, 64);
    d8  += __shfl_down(d8,  2, 64);  d8  += __shfl_down(d8,  1, 64);
    d16 += __shfl_down(d16, 2, 64);  d16 += __shfl_down(d16, 1, 64);
    d32 += __shfl_down(d32, 2, 64);  d32 += __shfl_down(d32, 1, 64);

    if (pp == 0) {
        const int gwi = bi * 8 + wi;
        const int gwj = bj * 8 + wj;
        if (gwi < OW && gwj < OW) {
            const float LN2 = 0.69314718055994530942f;
            const float num = 6.f * logf(d64) + 5.f * logf(d32) + 4.f * logf(d16)
                            + 3.f * logf(d8)  + 2.f * logf(d4);
            out[gwi * OW + gwj] = -num / (90.0f * LN2);
        }
    }
}

extern "C" void kernel_launch(void* const* d_in, const int* in_sizes, int n_in,
                              void* d_out, int out_size, void* d_ws, size_t ws_size,
                              hipStream_t stream) {
    const float* X = (const float*)d_in[0];
    float* out = (float*)d_out;
    fd_fused<<<15 * 15, 256, 0, stream>>>(X, out);
}

// Round 4
// 57.117 us; speedup vs baseline: 1.2180x; 1.0240x over previous
//
#include <hip/hip_runtime.h>
#include <math.h>

#define IMG_W 512
#define OW 113

__device__ __forceinline__ float max4f(float4 v) { return fmaxf(fmaxf(v.x, v.y), fmaxf(v.z, v.w)); }
__device__ __forceinline__ float min4f(float4 v) { return fminf(fminf(v.x, v.y), fminf(v.z, v.w)); }

// One block = one 8x8 patch of windows (grid 15x15). Builds a packed (max,min)
// tile pyramid for its 23x23-tile halo in LDS, piggybacks separable horizontal
// window sums (h4/h8/h16) into the pool phases, then each window needs only
// ~15 LDS reads in the final phase. 4 barriers total.
__global__ __launch_bounds__(256) void fd_fused(const float* __restrict__ X,
                                                float* __restrict__ out) {
    const int bi = blockIdx.x / 15;
    const int bj = blockIdx.x - bi * 15;
    const int t  = threadIdx.x;

    __shared__ float2 tmm[23][24];          // (max,min) of 4x4 px tiles
    __shared__ float2 p8[22][24];           // 8x8 px pools
    __shared__ float2 p16[20][24];          // 16x16
    __shared__ float2 p32[16][24];          // 32x32
    __shared__ float df4[23][25], df8[22][25], df16[20][25], df32[16][25];
    __shared__ float h4[23][9], h8[22][9], h16[20][9];   // horizontal window sums

    // ---- stage: per-4x4-tile max/min for the 23x23 halo ----
    for (int idx = t; idx < 23 * 23; idx += 256) {
        const int lr = idx / 23, lc = idx - lr * 23;
        const int gr = min(bi * 8 + lr, 127);   // clamped entries feed only guarded windows
        const int gc = min(bj * 8 + lc, 127);
        const float* p = X + (gr * 4) * IMG_W + gc * 4;
        float4 a = *(const float4*)(p);
        float4 b = *(const float4*)(p + IMG_W);
        float4 c = *(const float4*)(p + 2 * IMG_W);
        float4 d = *(const float4*)(p + 3 * IMG_W);
        float mx = fmaxf(fmaxf(max4f(a), max4f(b)), fmaxf(max4f(c), max4f(d)));
        float mn = fminf(fminf(min4f(a), min4f(b)), fminf(min4f(c), min4f(d)));
        tmm[lr][lc] = make_float2(mx, mn);
        df4[lr][lc] = mx - mn;
    }
    __syncthreads();

    // ---- P8 pool (22x22) + h4 horizontal sums (23x8) ----
    for (int idx = t; idx < 22 * 22; idx += 256) {
        const int lr = idx / 22, lc = idx - lr * 22;
        float2 q00 = tmm[lr][lc],     q01 = tmm[lr][lc + 1];
        float2 q10 = tmm[lr + 1][lc], q11 = tmm[lr + 1][lc + 1];
        float x = fmaxf(fmaxf(q00.x, q01.x), fmaxf(q10.x, q11.x));
        float n = fminf(fminf(q00.y, q01.y), fminf(q10.y, q11.y));
        p8[lr][lc] = make_float2(x, n);
        df8[lr][lc] = x - n;
    }
    if (t < 23 * 8) {
        const int r = t >> 3, wj = t & 7;
        float s = 0.f;
        #pragma unroll
        for (int b = 0; b < 16; ++b) s += df4[r][wj + b];
        h4[r][wj] = s;
    }
    __syncthreads();

    // ---- P16 pool (20x20) + h8 (22x8) ----
    for (int idx = t; idx < 20 * 20; idx += 256) {
        const int lr = idx / 20, lc = idx - lr * 20;
        float2 q00 = p8[lr][lc],     q01 = p8[lr][lc + 2];
        float2 q10 = p8[lr + 2][lc], q11 = p8[lr + 2][lc + 2];
        float x = fmaxf(fmaxf(q00.x, q01.x), fmaxf(q10.x, q11.x));
        float n = fminf(fminf(q00.y, q01.y), fminf(q10.y, q11.y));
        p16[lr][lc] = make_float2(x, n);
        df16[lr][lc] = x - n;
    }
    if (t < 22 * 8) {
        const int r = t >> 3, wj = t & 7;
        float s = 0.f;
        #pragma unroll
        for (int b = 0; b < 8; ++b) s += df8[r][wj + 2 * b];
        h8[r][wj] = s;
    }
    __syncthreads();

    // ---- P32 pool (16x16, exactly 256) + h16 (20x8) ----
    {
        const int lr = t >> 4, lc = t & 15;
        float2 q00 = p16[lr][lc],     q01 = p16[lr][lc + 4];
        float2 q10 = p16[lr + 4][lc], q11 = p16[lr + 4][lc + 4];
        float x = fmaxf(fmaxf(q00.x, q01.x), fmaxf(q10.x, q11.x));
        float n = fminf(fminf(q00.y, q01.y), fminf(q10.y, q11.y));
        p32[lr][lc] = make_float2(x, n);
        df32[lr][lc] = x - n;
    }
    if (t < 20 * 8) {
        const int r = t >> 3, wj = t & 7;
        float s = 0.f;
        #pragma unroll
        for (int b = 0; b < 4; ++b) s += df16[r][wj + 4 * b];
        h16[r][wj] = s;
    }
    __syncthreads();

    // ---- final: 4 threads per window, vertical combine of h sums ----
    const int q  = t >> 2;        // window 0..63
    const int pp = t & 3;         // part 0..3
    const int wi = q >> 3, wj = q & 7;

    float d4 = h4[wi + 4 * pp][wj]     + h4[wi + 4 * pp + 1][wj]
             + h4[wi + 4 * pp + 2][wj] + h4[wi + 4 * pp + 3][wj];
    float d8 = h8[wi + 4 * pp][wj] + h8[wi + 4 * pp + 2][wj];
    float d16 = h16[wi + 4 * pp][wj];
    float d32 = 0.f, d64 = 0.f;
    if (pp < 2) d32 = df32[wi + 8 * pp][wj] + df32[wi + 8 * pp][wj + 8];
    if (pp == 0) {
        float2 a0 = p32[wi][wj],     a1 = p32[wi][wj + 8];
        float2 a2 = p32[wi + 8][wj], a3 = p32[wi + 8][wj + 8];
        d64 = fmaxf(fmaxf(a0.x, a1.x), fmaxf(a2.x, a3.x))
            - fminf(fminf(a0.y, a1.y), fminf(a2.y, a3.y));
    }

    d4  += __shfl_down(d4,  2, 64);  d4  += __shfl_down(d4,  1, 64);
    d8  += __shfl_down(d8,  2, 64);  d8  += __shfl_down(d8,  1, 64);
    d16 += __shfl_down(d16, 2, 64);  d16 += __shfl_down(d16, 1, 64);
    d32 += __shfl_down(d32, 1, 64);  // p0 += p1 (p2/p3 are 0)

    if (pp == 0) {
        const int gwi = bi * 8 + wi;
        const int gwj = bj * 8 + wj;
        if (gwi < OW && gwj < OW) {
            const float LN2 = 0.69314718055994530942f;
            const float num = 6.f * logf(d64) + 5.f * logf(d32) + 4.f * logf(d16)
                            + 3.f * logf(d8)  + 2.f * logf(d4);
            out[gwi * OW + gwj] = -num / (90.0f * LN2);
        }
    }
}

extern "C" void kernel_launch(void* const* d_in, const int* in_sizes, int n_in,
                              void* d_out, int out_size, void* d_ws, size_t ws_size,
                              hipStream_t stream) {
    const float* X = (const float*)d_in[0];
    float* out = (float*)d_out;
    fd_fused<<<15 * 15, 256, 0, stream>>>(X, out);
}